// Round 15
// baseline (154.340 us; speedup 1.0000x reference)
//
#include <hip/hip_runtime.h>

// RecurrentDecoder: B=8192, T=100, I=30, H=100.
// R15: K-augmented MFMA — x, bias, and W_d folded into the matmul.
// h_aug channels: [h 0..99 | dead 100..111 | x 112..141 | 1.0 @142 | 0 pad], K=160.
// W columns (pre-scaled by -log2e / -2log2e): rows 0-99 = Whh, 112-141 = Wih,
// 142 = bih+bhh. Dead col 101 = W_d (unscaled, bd in row 142) -> po by MFMA.
// 512 blocks x 448 threads (7 waves, B-tile 16, identity unit map, no po-wave).
// wfrag 80 AGPR + ~46 VGPR <= 128 -> 2 blocks/CU -> 3-4 waves/SIMD.
// ks-outer MFMA (4 indep chains of 5), packed-f32 acts (7 trans/cell),
// 1 barrier/step, no VMEM in loop.

#define LOG2E 1.44269504088896340736f

typedef _Float16 f16x8 __attribute__((ext_vector_type(8)));
typedef float    f32x4 __attribute__((ext_vector_type(4)));
typedef float    f32x2 __attribute__((ext_vector_type(2)));

__device__ __forceinline__ float rcp_(float x) { return __builtin_amdgcn_rcpf(x); }
__device__ __forceinline__ float exp2_(float x) { return __builtin_amdgcn_exp2f(x); }

#define KS2 168   // k-stride in halves (336 B = 21*16 B: aligned, conflict-free)

__global__ __launch_bounds__(448, 4) void lstm_kernel(
    const float* __restrict__ x, const float* __restrict__ Wih,
    const float* __restrict__ Whh, const float* __restrict__ bih,
    const float* __restrict__ bhh, const float* __restrict__ Wd,
    const float* __restrict__ bd, float* __restrict__ out)
{
    __shared__ __align__(16) char smem[128 * KS2 * 2];    // Wstg(43008) U outb(6400)
    __shared__ __align__(16) _Float16 hlds[2][16 * KS2];  // 10752 B (dbuf)
    // total 53760 B -> 2 blocks/CU

    _Float16* Wstg = (_Float16*)smem;
    float*    outb = (float*)smem;

    const int tid = threadIdx.x;
    const int w   = tid >> 6;      // wave 0..6 -> units w*16..w*16+15
    const int l   = tid & 63;
    const int g   = l >> 4;        // 0..3 -> C rows 4g..4g+3
    const int c   = l & 15;        // col within tile / A row
    const int b0  = blockIdx.x * 16;
    const int u   = w * 16 + c;    // unit 0..111 (100..111 dead)
    const bool wpo = (w == 6) && (c == 5);   // owner of po column (col 101)

    // ---- zero LDS (covers dead cols/channels; h(-1)=0) ----
    for (int i = tid; i < 128 * KS2 / 2; i += 448) ((unsigned*)Wstg)[i] = 0u;
    for (int i = tid; i < 2 * 16 * KS2 / 2; i += 448) ((unsigned*)&hlds[0][0])[i] = 0u;
    __syncthreads();

    // ---- constant channels into BOTH h buffers: x @112..141, 1.0 @142 ----
    for (int idx = tid; idx < 960; idx += 448) {
        int buf = idx / 480, rem = idx - buf * 480;
        int rr = rem / 30, kk = rem - rr * 30;
        hlds[buf][rr * KS2 + 112 + kk] = (_Float16)x[(b0 + rr) * 30 + kk];
    }
    if (tid < 32) hlds[tid >> 4][(tid & 15) * KS2 + 142] = (_Float16)1.0f;

    // ---- chunked W staging (one gate per chunk), pre-scaled, identity cols.
    //      Rows 0-99 Whh, 112-141 Wih, 142 bias. s=0: col 101 = W_d, bd@142. ----
    f16x8 wfrag[4][5];
    for (int s = 0; s < 4; ++s) {
        const float sc = (s == 2) ? (-2.0f * LOG2E) : (-LOG2E);
        for (int idx = tid; idx < 13100; idx += 448) {
            if (idx < 10000) {
                int uu = idx / 100, k = idx - uu * 100;
                Wstg[uu * KS2 + k] = (_Float16)(Whh[(s * 100 + uu) * 100 + k] * sc);
            } else if (idx < 13000) {
                int j = idx - 10000, uu = j / 30, k = j - uu * 30;
                Wstg[uu * KS2 + 112 + k] = (_Float16)(Wih[(s * 100 + uu) * 30 + k] * sc);
            } else {
                int uu = idx - 13000;
                Wstg[uu * KS2 + 142] =
                    (_Float16)((bih[s * 100 + uu] + bhh[s * 100 + uu]) * sc);
            }
        }
        if (s == 0) {
            for (int k = tid; k < 100; k += 448)
                Wstg[101 * KS2 + k] = (_Float16)Wd[k];
            if (tid == 0) Wstg[101 * KS2 + 142] = (_Float16)bd[0];
        }
        __syncthreads();
        #pragma unroll
        for (int ks = 0; ks < 5; ++ks)
            wfrag[s][ks] = *(const f16x8*)&Wstg[u * KS2 + ks * 32 + g * 8];
        __syncthreads();
    }
    // (cols 100,102-111 stay zero; col 101 keeps W_d for s>=1 chunks -- its
    //  lane computes garbage acts whose h lands in zero-row channel 101.)

    f32x2 creg2[2] = {{0.f, 0.f}, {0.f, 0.f}};
    __syncthreads();   // x-channels + staging all visible

    const int afb = c * KS2 + g * 8;   // A-frag base (+ks*32)

    // one LSTM step; P = buffer parity (compile-time), TCUR = step index
#define STEP(P, TCUR)                                                         \
    {                                                                         \
        const _Float16* hr = &hlds[(P)][0];                                   \
        _Float16*       hw = &hlds[(P) ^ 1][0];                               \
        f32x4 acc[4];                                                         \
        _Pragma("unroll")                                                     \
        for (int s = 0; s < 4; ++s) acc[s] = (f32x4){0.f, 0.f, 0.f, 0.f};     \
        _Pragma("unroll")                                                     \
        for (int ks = 0; ks < 5; ++ks) {                                      \
            f16x8 a = *(const f16x8*)&hr[afb + ks * 32];                      \
            _Pragma("unroll")                                                 \
            for (int s = 0; s < 4; ++s)                                       \
                acc[s] = __builtin_amdgcn_mfma_f32_16x16x32_f16(              \
                        a, wfrag[s][ks], acc[s], 0, 0, 0);                    \
        }                                                                     \
        /* po(t-1) = h_aug(t-1)@[W_d;bd] in the col-101 lane's acc[0] */      \
        if ((TCUR) > 0 && wpo) {                                              \
            _Pragma("unroll")                                                 \
            for (int r = 0; r < 4; ++r)                                       \
                outb[(4 * g + r) * 100 + (TCUR) - 1] = acc[0][r];             \
        }                                                                     \
        /* packed-f32 activations on row-pairs q */                           \
        _Pragma("unroll")                                                     \
        for (int q = 0; q < 2; ++q) {                                         \
            f32x2 A2 = {exp2_(acc[0][2 * q]), exp2_(acc[0][2 * q + 1])};      \
            f32x2 F2 = {exp2_(acc[1][2 * q]), exp2_(acc[1][2 * q + 1])};      \
            f32x2 G2 = {exp2_(acc[2][2 * q]), exp2_(acc[2][2 * q + 1])};      \
            f32x2 O2 = {exp2_(acc[3][2 * q]), exp2_(acc[3][2 * q + 1])};      \
            f32x2 a1 = A2 + 1.0f;                                             \
            f32x2 f1 = F2 + 1.0f;                                             \
            f32x2 g1 = G2 + 1.0f;                                             \
            f32x2 gm = 1.0f - G2;                                             \
            f32x2 ag = a1 * g1;                                               \
            f32x2 num = creg2[q] * ag + gm * f1;                              \
            f32x2 den = ag * f1;                                              \
            f32x2 rd = {rcp_(den[0]), rcp_(den[1])};                          \
            f32x2 cg = num * rd;                                              \
            creg2[q] = cg;                                                    \
            f32x2 cgk = cg * (-2.0f * LOG2E);                                 \
            f32x2 C2 = {exp2_(cgk[0]), exp2_(cgk[1])};                        \
            f32x2 c2m = 1.0f - C2;                                            \
            f32x2 od = (O2 + 1.0f) * (C2 + 1.0f);                             \
            f32x2 ro = {rcp_(od[0]), rcp_(od[1])};                            \
            f32x2 hv = c2m * ro;                                              \
            hw[(4 * g + 2 * q) * KS2 + u]     = (_Float16)hv[0];              \
            hw[(4 * g + 2 * q + 1) * KS2 + u] = (_Float16)hv[1];              \
        }                                                                     \
        __syncthreads();                                                      \
    }

    for (int t2 = 0; t2 < 50; ++t2) {
        STEP(0, 2 * t2);
        STEP(1, 2 * t2 + 1);
    }
#undef STEP

    // epilogue: po(99) from h(99) (in hlds[0])
    {
        f32x4 a99 = {0.f, 0.f, 0.f, 0.f};
        #pragma unroll
        for (int ks = 0; ks < 5; ++ks) {
            f16x8 a = *(const f16x8*)&hlds[0][afb + ks * 32];
            a99 = __builtin_amdgcn_mfma_f32_16x16x32_f16(a, wfrag[0][ks], a99, 0, 0, 0);
        }
        if (wpo) {
            #pragma unroll
            for (int r = 0; r < 4; ++r)
                outb[(4 * g + r) * 100 + 99] = a99[r];
        }
    }
    __syncthreads();

    // coalesced vector write of the block's 16x100 outputs
    {
        f32x4*       o4 = (f32x4*)(out + b0 * 100);
        const f32x4* s4 = (const f32x4*)outb;
        for (int i = tid; i < 400; i += 448) o4[i] = s4[i];
    }
}

extern "C" void kernel_launch(void* const* d_in, const int* in_sizes, int n_in,
                              void* d_out, int out_size, void* d_ws, size_t ws_size,
                              hipStream_t stream) {
    (void)in_sizes; (void)n_in; (void)out_size; (void)d_ws; (void)ws_size;
    const float* x   = (const float*)d_in[0];
    const float* Wih = (const float*)d_in[1];
    const float* Whh = (const float*)d_in[2];
    const float* bih = (const float*)d_in[3];
    const float* bhh = (const float*)d_in[4];
    const float* Wd  = (const float*)d_in[5];
    const float* bd  = (const float*)d_in[6];
    lstm_kernel<<<dim3(512), dim3(448), 0, stream>>>(
        x, Wih, Whh, bih, bhh, Wd, bd, (float*)d_out);
}

// Round 17
// 138.655 us; speedup vs baseline: 1.1131x; 1.1131x over previous
//
#include <hip/hip_runtime.h>

// RecurrentDecoder: B=8192, T=100, I=30, H=100.
// R17 = R16 with the xq swizzle row-stride bug fixed (XQR 272 -> 288; lane 63
// needs words up to 284). 512 blocks x 448 threads (7 waves), B-tile 16.
// Dead col 101 = W_d -> col-101 lanes' acc[0] is the decoder output po after
// the normal MFMA pass (no dedicated po-wave). xq in bank-swizzled LDS
// (addr = l*4 + (l>>3)*4, 2-way max). wfrag 64 AGPR + ~64 VGPR -> 2 blocks/CU.
// ks-outer MFMA, packed-f32 merged-rcp acts (7 trans/cell), 1 barrier/step,
// no VMEM in loop.

#define LOG2E 1.44269504088896340736f

typedef _Float16 f16x8 __attribute__((ext_vector_type(8)));
typedef float    f32x4 __attribute__((ext_vector_type(4)));
typedef float    f32x2 __attribute__((ext_vector_type(2)));

__device__ __forceinline__ float rcp_(float x) { return __builtin_amdgcn_rcpf(x); }
__device__ __forceinline__ float exp2_(float x) { return __builtin_amdgcn_exp2f(x); }

#define KS 136     // f16 k-stride (272 B = 17*16 B; 2-way max on af reads)
#define XQR 288    // xq row stride in words (covers swizzled offsets up to 284)

__global__ __launch_bounds__(448, 4) void lstm_kernel(
    const float* __restrict__ x, const float* __restrict__ Wih,
    const float* __restrict__ Whh, const float* __restrict__ bih,
    const float* __restrict__ bhh, const float* __restrict__ Wd,
    const float* __restrict__ bd, float* __restrict__ out)
{
    __shared__ __align__(16) char smem[128 * KS * 2];      // Wstg(34816) U outb(6400)
    __shared__ __align__(16) _Float16 hlds[2][16 * KS];    //  8704 B (dbuf)
    __shared__ __align__(16) float xq_lds[7 * 4 * XQR];    // 32256 B (swizzled)
    // total 75776 B -> 2 blocks/CU

    _Float16* Wstg = (_Float16*)smem;
    float*    outb = (float*)smem;

    const int tid = threadIdx.x;
    const int w   = tid >> 6;      // wave 0..6 -> units w*16..w*16+15
    const int l   = tid & 63;
    const int g   = l >> 4;        // 0..3 -> C rows 4g..4g+3
    const int c   = l & 15;        // col within tile / A row
    const int b0  = blockIdx.x * 16;
    const int u   = w * 16 + c;    // unit 0..111 (100..111 dead; 101 = W_d col)
    const bool wpo = (u == 101);   // po-column owner lanes (one per g)

    // ---- zero LDS (covers dead cols/channels; h(-1)=0) ----
    for (int i = tid; i < 128 * KS / 2; i += 448) ((unsigned*)Wstg)[i] = 0u;
    for (int i = tid; i < 2 * 16 * KS / 2; i += 448) ((unsigned*)&hlds[0][0])[i] = 0u;
    __syncthreads();

    // ---- chunked W staging (one gate per chunk), pre-scaled, identity cols.
    //      s=0 chunk also stages W_d (unscaled) into dead col 101. ----
    f16x8 wfrag[4][4];   // [s][ks]
    for (int s = 0; s < 4; ++s) {
        const float sc = (s == 2) ? (-2.0f * LOG2E) : (-LOG2E);
        for (int idx = tid; idx < 10000; idx += 448) {
            int uu = idx / 100, k = idx - uu * 100;
            Wstg[uu * KS + k] = (_Float16)(Whh[(s * 100 + uu) * 100 + k] * sc);
        }
        if (s == 0)
            for (int k = tid; k < 100; k += 448)
                Wstg[101 * KS + k] = (_Float16)Wd[k];
        __syncthreads();
        #pragma unroll
        for (int ks = 0; ks < 4; ++ks)
            wfrag[s][ks] = *(const f16x8*)&Wstg[u * KS + ks * 32 + g * 8];
        __syncthreads();
    }
    // (col-101 lane: wfrag[0] = W_d column; wfrag[1..3] = zero columns ->
    //  garbage-but-finite acts; its h lands in channel 101 whose W K-rows are
    //  zero, so nothing propagates.)

    // ---- xq -> swizzled LDS (pre-scaled gate pre-acts incl. bias) ----
    const int xqsw = l * 4 + ((l >> 3) << 2);   // 2-way-max b128 swizzle
    {
        float xq[4][4];
        #pragma unroll
        for (int s = 0; s < 4; ++s)
            #pragma unroll
            for (int r = 0; r < 4; ++r) xq[s][r] = 0.0f;
        if (u < 100) {
            for (int k = 0; k < 30; ++k) {
                float xv[4];
                #pragma unroll
                for (int r = 0; r < 4; ++r) xv[r] = x[(b0 + 4 * g + r) * 30 + k];
                #pragma unroll
                for (int s = 0; s < 4; ++s) {
                    float wv = Wih[(s * 100 + u) * 30 + k];
                    #pragma unroll
                    for (int r = 0; r < 4; ++r) xq[s][r] += xv[r] * wv;
                }
            }
            #pragma unroll
            for (int s = 0; s < 4; ++s) {
                float sc = (s == 2) ? (-2.0f * LOG2E) : (-LOG2E);
                float b  = bih[s * 100 + u] + bhh[s * 100 + u];
                #pragma unroll
                for (int r = 0; r < 4; ++r) xq[s][r] = (xq[s][r] + b) * sc;
            }
        }
        #pragma unroll
        for (int s = 0; s < 4; ++s) {
            f32x4 v = {xq[s][0], xq[s][1], xq[s][2], xq[s][3]};
            *(f32x4*)&xq_lds[(w * 4 + s) * XQR + xqsw] = v;
        }
    }
    const float bdv = bd[0];
    f32x2 creg2[2] = {{0.f, 0.f}, {0.f, 0.f}};
    __syncthreads();

    const int afb = c * KS + g * 8;                 // A-frag base (+ks*32)
    const int xqb = w * 4 * XQR + xqsw;             // xq base (+s*XQR)

    // acc persists across steps: holds next step's C-init (xq, prefetched
    // pre-barrier into the dead registers).
    f32x4 acc[4];
    #pragma unroll
    for (int s = 0; s < 4; ++s)
        acc[s] = *(const f32x4*)&xq_lds[xqb + s * XQR];
    __syncthreads();

    // one LSTM step; P = buffer parity (compile-time), TCUR = step index
#define STEP(P, TCUR)                                                         \
    {                                                                         \
        const _Float16* hr = &hlds[(P)][0];                                   \
        _Float16*       hw = &hlds[(P) ^ 1][0];                               \
        f16x8 af[4];                                                          \
        _Pragma("unroll")                                                     \
        for (int ks = 0; ks < 4; ++ks)                                        \
            af[ks] = *(const f16x8*)&hr[afb + ks * 32];                       \
        _Pragma("unroll")                                                     \
        for (int ks = 0; ks < 4; ++ks)                                        \
            _Pragma("unroll")                                                 \
            for (int s = 0; s < 4; ++s)                                       \
                acc[s] = __builtin_amdgcn_mfma_f32_16x16x32_f16(              \
                        af[ks], wfrag[s][ks], acc[s], 0, 0, 0);               \
        /* po(t-1) = h(t-1)@W_d sits in the col-101 lanes' acc[0] */          \
        if ((TCUR) > 0 && wpo) {                                              \
            _Pragma("unroll")                                                 \
            for (int r = 0; r < 4; ++r)                                       \
                outb[(4 * g + r) * 100 + (TCUR) - 1] = acc[0][r] + bdv;       \
        }                                                                     \
        /* packed-f32 activations on row-pairs q */                           \
        _Pragma("unroll")                                                     \
        for (int q = 0; q < 2; ++q) {                                         \
            f32x2 A2 = {exp2_(acc[0][2 * q]), exp2_(acc[0][2 * q + 1])};      \
            f32x2 F2 = {exp2_(acc[1][2 * q]), exp2_(acc[1][2 * q + 1])};      \
            f32x2 G2 = {exp2_(acc[2][2 * q]), exp2_(acc[2][2 * q + 1])};      \
            f32x2 O2 = {exp2_(acc[3][2 * q]), exp2_(acc[3][2 * q + 1])};      \
            f32x2 a1 = A2 + 1.0f;                                             \
            f32x2 f1 = F2 + 1.0f;                                             \
            f32x2 g1 = G2 + 1.0f;                                             \
            f32x2 gm = 1.0f - G2;                                             \
            f32x2 ag = a1 * g1;                                               \
            f32x2 num = creg2[q] * ag + gm * f1;                              \
            f32x2 den = ag * f1;                                              \
            f32x2 rd = {rcp_(den[0]), rcp_(den[1])};                          \
            f32x2 cg = num * rd;                                              \
            creg2[q] = cg;                                                    \
            f32x2 cgk = cg * (-2.0f * LOG2E);                                 \
            f32x2 C2 = {exp2_(cgk[0]), exp2_(cgk[1])};                        \
            f32x2 c2m = 1.0f - C2;                                            \
            f32x2 od = (O2 + 1.0f) * (C2 + 1.0f);                             \
            f32x2 ro = {rcp_(od[0]), rcp_(od[1])};                            \
            f32x2 hv = c2m * ro;                                              \
            hw[(4 * g + 2 * q) * KS + u]     = (_Float16)hv[0];               \
            hw[(4 * g + 2 * q + 1) * KS + u] = (_Float16)hv[1];               \
        }                                                                     \
        /* prefetch next step's C-init while the LDS pipe is idle */          \
        _Pragma("unroll")                                                     \
        for (int s = 0; s < 4; ++s)                                           \
            acc[s] = *(const f32x4*)&xq_lds[xqb + s * XQR];                   \
        __syncthreads();                                                      \
    }

    for (int t2 = 0; t2 < 50; ++t2) {
        STEP(0, 2 * t2);
        STEP(1, 2 * t2 + 1);
    }
#undef STEP

    // epilogue: po(99) from h(99) (in hlds[0]) via one more s=0 MFMA chain
    {
        f32x4 a99 = {0.f, 0.f, 0.f, 0.f};
        #pragma unroll
        for (int ks = 0; ks < 4; ++ks) {
            f16x8 a = *(const f16x8*)&hlds[0][afb + ks * 32];
            a99 = __builtin_amdgcn_mfma_f32_16x16x32_f16(a, wfrag[0][ks], a99, 0, 0, 0);
        }
        if (wpo) {
            #pragma unroll
            for (int r = 0; r < 4; ++r)
                outb[(4 * g + r) * 100 + 99] = a99[r] + bdv;
        }
    }
    __syncthreads();

    // coalesced vector write of the block's 16x100 outputs
    {
        f32x4*       o4 = (f32x4*)(out + b0 * 100);
        const f32x4* s4 = (const f32x4*)outb;
        for (int i = tid; i < 400; i += 448) o4[i] = s4[i];
    }
}

extern "C" void kernel_launch(void* const* d_in, const int* in_sizes, int n_in,
                              void* d_out, int out_size, void* d_ws, size_t ws_size,
                              hipStream_t stream) {
    (void)in_sizes; (void)n_in; (void)out_size; (void)d_ws; (void)ws_size;
    const float* x   = (const float*)d_in[0];
    const float* Wih = (const float*)d_in[1];
    const float* Whh = (const float*)d_in[2];
    const float* bih = (const float*)d_in[3];
    const float* bhh = (const float*)d_in[4];
    const float* Wd  = (const float*)d_in[5];
    const float* bd  = (const float*)d_in[6];
    lstm_kernel<<<dim3(512), dim3(448), 0, stream>>>(
        x, Wih, Whh, bih, bhh, Wd, bd, (float*)d_out);
}